// Round 1
// baseline (66.425 us; speedup 1.0000x reference)
//
#include <hip/hip_runtime.h>
#include <hip/hip_bf16.h>

#define T_TOTAL 200000
#define INV2PI 0.15915494309189535f

// Parameter block layout (floats):
// [0 .. 39]     : layer0 interleaved pairs (ww0', ph0') x 20
// [40 .. 59]    : A0 x 20
// [60 .. 1059]  : layer1 interleaved pairs (ww1', ph1') x 500   (row-major m*20+n)
// [1060 .. 2559]: layer2 interleaved pairs (ww2', ph2') x 750   (row-major m*25+n)
// [2560 .. 2619]: layer3 interleaved pairs (ww3', ph3') x 30
// Total 2620 floats. ww'/ph' are pre-divided by 2*pi so the main kernel can use
// raw v_sin_f32 (revolutions) with a single v_fract for range reduction.
__device__ float g_P[2620];

__device__ __forceinline__ float relu_f(float x) { return fmaxf(x, 0.0f); }

// sin(2*pi*rev) via hardware v_sin_f32; rev >= 0 here (all params/t nonneg).
__device__ __forceinline__ float sin_rev(float rev) {
    return __builtin_amdgcn_sinf(__builtin_amdgcn_fractf(rev));
}

__global__ void prep_kernel(
    const float* __restrict__ A0,
    const float* __restrict__ w0, const float* __restrict__ phi0,
    const float* __restrict__ wc0, const float* __restrict__ phic0,
    const float* __restrict__ w1, const float* __restrict__ phi1,
    const float* __restrict__ wc1, const float* __restrict__ phic1,
    const float* __restrict__ w2, const float* __restrict__ phi2,
    const float* __restrict__ wc2, const float* __restrict__ phic2,
    const float* __restrict__ w3, const float* __restrict__ phi3,
    const float* __restrict__ wc3, const float* __restrict__ phic3)
{
    const int tid = blockIdx.x * blockDim.x + threadIdx.x;
    const int stride = blockDim.x * gridDim.x;

    const float ws0 = relu_f(wc0[0]), ps0 = relu_f(phic0[0]);
    const float ws1 = relu_f(wc1[0]), ps1 = relu_f(phic1[0]);
    const float ws2 = relu_f(wc2[0]), ps2 = relu_f(phic2[0]);
    const float ws3 = relu_f(wc3[0]), ps3 = relu_f(phic3[0]);

    for (int n = tid; n < 20; n += stride) {
        g_P[2 * n]     = (relu_f(w0[n])   + ws0) * INV2PI;
        g_P[2 * n + 1] = (relu_f(phi0[n]) + ps0) * INV2PI;
        g_P[40 + n]    = A0[n];
    }
    for (int k = tid; k < 500; k += stride) {
        g_P[60 + 2 * k]     = (relu_f(w1[k])   + ws1) * INV2PI;
        g_P[60 + 2 * k + 1] = (relu_f(phi1[k]) + ps1) * INV2PI;
    }
    for (int k = tid; k < 750; k += stride) {
        g_P[1060 + 2 * k]     = (relu_f(w2[k])   + ws2) * INV2PI;
        g_P[1060 + 2 * k + 1] = (relu_f(phi2[k]) + ps2) * INV2PI;
    }
    for (int k = tid; k < 30; k += stride) {
        g_P[2560 + 2 * k]     = (relu_f(w3[k])   + ws3) * INV2PI;
        g_P[2560 + 2 * k + 1] = (relu_f(phi3[k]) + ps3) * INV2PI;
    }
}

__launch_bounds__(256, 2)
__global__ void wave_main(float* __restrict__ out)
{
    const int t = blockIdx.x * 256 + threadIdx.x;
    if (t >= T_TOTAL) return;
    // tvec = linspace(1, 1000, T) in fp32
    const float tv = fmaf((float)t, 999.0f / 199999.0f, 1.0f);

    // ---- layer 0: s0[n] = A0[n] * sin(ww0[n]*t + ph0[n]) ----
    float s0[20];
    float sum0 = 0.0f;
#pragma unroll
    for (int n = 0; n < 20; ++n) {
        float rev = fmaf(g_P[2 * n], tv, g_P[2 * n + 1]);
        s0[n] = g_P[40 + n] * sin_rev(rev);
        sum0 += s0[n];
    }

    // ---- layer 1: s1[m] = sum_n (0.5*sin(..)+0.5)*s0[n] = 0.5*acc + 0.5*sum0
    float s1[25];
    float sum1 = 0.0f;
#pragma unroll
    for (int m = 0; m < 25; ++m) {
        float acc = 0.0f;
#pragma unroll
        for (int n = 0; n < 20; ++n) {
            const int k = 60 + 2 * (m * 20 + n);
            float rev = fmaf(g_P[k], tv, g_P[k + 1]);
            acc = fmaf(sin_rev(rev), s0[n], acc);
        }
        s1[m] = fmaf(0.5f, acc, 0.5f * sum0);
        sum1 += s1[m];
    }

    // ---- layer 2 ----
    float s2[30];
    float sum2 = 0.0f;
#pragma unroll
    for (int m = 0; m < 30; ++m) {
        float acc = 0.0f;
#pragma unroll
        for (int n = 0; n < 25; ++n) {
            const int k = 1060 + 2 * (m * 25 + n);
            float rev = fmaf(g_P[k], tv, g_P[k + 1]);
            acc = fmaf(sin_rev(rev), s1[n], acc);
        }
        s2[m] = fmaf(0.5f, acc, 0.5f * sum1);
        sum2 += s2[m];
    }

    // ---- layer 3 (single output row) ----
    float acc3 = 0.0f;
#pragma unroll
    for (int n = 0; n < 30; ++n) {
        const int k = 2560 + 2 * n;
        float rev = fmaf(g_P[k], tv, g_P[k + 1]);
        acc3 = fmaf(sin_rev(rev), s2[n], acc3);
    }
    out[t] = fmaf(0.5f, acc3, 0.5f * sum2);
}

extern "C" void kernel_launch(void* const* d_in, const int* in_sizes, int n_in,
                              void* d_out, int out_size, void* d_ws, size_t ws_size,
                              hipStream_t stream) {
    (void)in_sizes; (void)n_in; (void)d_ws; (void)ws_size;
    // Input order per setup_inputs():
    // 0: initial_wave_input (unused)
    // 1: A0  2: w0  3: phi0  4: wc0  5: phic0
    // 6: w1  7: phi1  8: wc1  9: phic1
    // 10: w2 11: phi2 12: wc2 13: phic2
    // 14: w3 15: phi3 16: wc3 17: phic3
    const float* A0    = (const float*)d_in[1];
    const float* w0    = (const float*)d_in[2];
    const float* phi0  = (const float*)d_in[3];
    const float* wc0   = (const float*)d_in[4];
    const float* phic0 = (const float*)d_in[5];
    const float* w1    = (const float*)d_in[6];
    const float* phi1  = (const float*)d_in[7];
    const float* wc1   = (const float*)d_in[8];
    const float* phic1 = (const float*)d_in[9];
    const float* w2    = (const float*)d_in[10];
    const float* phi2  = (const float*)d_in[11];
    const float* wc2   = (const float*)d_in[12];
    const float* phic2 = (const float*)d_in[13];
    const float* w3    = (const float*)d_in[14];
    const float* phi3  = (const float*)d_in[15];
    const float* wc3   = (const float*)d_in[16];
    const float* phic3 = (const float*)d_in[17];

    float* out = (float*)d_out;

    hipLaunchKernelGGL(prep_kernel, dim3(11), dim3(256), 0, stream,
                       A0, w0, phi0, wc0, phic0,
                       w1, phi1, wc1, phic1,
                       w2, phi2, wc2, phic2,
                       w3, phi3, wc3, phic3);

    const int grid = (out_size + 255) / 256;
    hipLaunchKernelGGL(wave_main, dim3(grid), dim3(256), 0, stream, out);
}

// Round 2
// 62.680 us; speedup vs baseline: 1.0597x; 1.0597x over previous
//
#include <hip/hip_runtime.h>
#include <hip/hip_bf16.h>

#define T_TOTAL 200000
#define INV2PI 0.15915494309189535f

// Parameter block layout (floats):
// [0 .. 39]     : layer0 interleaved pairs (ww0', ph0') x 20
// [40 .. 59]    : A0 x 20
// [60 .. 1059]  : layer1 pairs stored COLUMN-major: offset 60 + 2*(n*25+m), n<20, m<25
// [1060 .. 2559]: layer2 pairs stored COLUMN-major: offset 1060 + 2*(n*30+m), n<25, m<30
// [2560 .. 2619]: layer3 interleaved pairs x 30
// ww'/ph' pre-divided by 2*pi so the main kernel uses raw v_sin_f32
// (revolutions) with a single v_fract for range reduction.
__device__ float g_P[2620];

__device__ __forceinline__ float relu_f(float x) { return fmaxf(x, 0.0f); }

// sin(2*pi*rev) via hardware v_sin_f32; rev >= 0 here (all params/t nonneg).
__device__ __forceinline__ float sin_rev(float rev) {
    return __builtin_amdgcn_sinf(__builtin_amdgcn_fractf(rev));
}

__global__ void prep_kernel(
    const float* __restrict__ A0,
    const float* __restrict__ w0, const float* __restrict__ phi0,
    const float* __restrict__ wc0, const float* __restrict__ phic0,
    const float* __restrict__ w1, const float* __restrict__ phi1,
    const float* __restrict__ wc1, const float* __restrict__ phic1,
    const float* __restrict__ w2, const float* __restrict__ phi2,
    const float* __restrict__ wc2, const float* __restrict__ phic2,
    const float* __restrict__ w3, const float* __restrict__ phi3,
    const float* __restrict__ wc3, const float* __restrict__ phic3)
{
    const int tid = blockIdx.x * blockDim.x + threadIdx.x;
    const int stride = blockDim.x * gridDim.x;

    const float ws0 = relu_f(wc0[0]), ps0 = relu_f(phic0[0]);
    const float ws1 = relu_f(wc1[0]), ps1 = relu_f(phic1[0]);
    const float ws2 = relu_f(wc2[0]), ps2 = relu_f(phic2[0]);
    const float ws3 = relu_f(wc3[0]), ps3 = relu_f(phic3[0]);

    for (int n = tid; n < 20; n += stride) {
        g_P[2 * n]     = (relu_f(w0[n])   + ws0) * INV2PI;
        g_P[2 * n + 1] = (relu_f(phi0[n]) + ps0) * INV2PI;
        g_P[40 + n]    = A0[n];
    }
    for (int k = tid; k < 500; k += stride) {
        const int m = k / 20, n = k % 20;           // source row-major (m,n)
        const int d = 60 + 2 * (n * 25 + m);        // dest column-major
        g_P[d]     = (relu_f(w1[k])   + ws1) * INV2PI;
        g_P[d + 1] = (relu_f(phi1[k]) + ps1) * INV2PI;
    }
    for (int k = tid; k < 750; k += stride) {
        const int m = k / 25, n = k % 25;
        const int d = 1060 + 2 * (n * 30 + m);
        g_P[d]     = (relu_f(w2[k])   + ws2) * INV2PI;
        g_P[d + 1] = (relu_f(phi2[k]) + ps2) * INV2PI;
    }
    for (int k = tid; k < 30; k += stride) {
        g_P[2560 + 2 * k]     = (relu_f(w3[k])   + ws3) * INV2PI;
        g_P[2560 + 2 * k + 1] = (relu_f(phi3[k]) + ps3) * INV2PI;
    }
}

// block = 64 (one wave). Cross-layer vectors staged in LDS so the outer
// (n) loops stay ROLLED (small code, I$-resident) while the inner (m)
// accumulator loops are unrolled (compile-time register indices).
__launch_bounds__(64)
__global__ void wave_main(float* __restrict__ out)
{
    __shared__ float sh0[20 * 64];   // s0 staged per-thread, [n*64+tid]
    __shared__ float sh1[25 * 64];   // s1 staged per-thread

    const int tid = threadIdx.x;
    const int t = blockIdx.x * 64 + tid;
    // tvec = linspace(1, 1000, T)
    const float tv = fmaf((float)t, 999.0f / 199999.0f, 1.0f);

    // ---- layer 0: s0[n] = A0[n] * sin(ww*t + ph) -> LDS ----
    float sum0 = 0.0f;
#pragma unroll
    for (int n = 0; n < 20; ++n) {
        float rev = fmaf(g_P[2 * n], tv, g_P[2 * n + 1]);
        float v = g_P[40 + n] * sin_rev(rev);
        sh0[n * 64 + tid] = v;
        sum0 += v;
    }

    // ---- layer 1: acc1[m] += sin(p[m,n]) * s0[n], n rolled / m unrolled ----
    float acc1[25];
#pragma unroll
    for (int m = 0; m < 25; ++m) acc1[m] = 0.0f;
    __syncthreads();
    for (int n = 0; n < 20; ++n) {
        const float s0n = sh0[n * 64 + tid];
        const float* __restrict__ p = &g_P[60 + 50 * n];   // 25 contiguous pairs
#pragma unroll
        for (int m = 0; m < 25; ++m) {
            float rev = fmaf(p[2 * m], tv, p[2 * m + 1]);
            acc1[m] = fmaf(sin_rev(rev), s0n, acc1[m]);
        }
    }
    float sum1 = 0.0f;
#pragma unroll
    for (int m = 0; m < 25; ++m) {
        float v = fmaf(0.5f, acc1[m], 0.5f * sum0);
        sh1[m * 64 + tid] = v;
        sum1 += v;
    }

    // ---- layer 2 ----
    float acc2[30];
#pragma unroll
    for (int m = 0; m < 30; ++m) acc2[m] = 0.0f;
    __syncthreads();
    for (int n = 0; n < 25; ++n) {
        const float s1n = sh1[n * 64 + tid];
        const float* __restrict__ p = &g_P[1060 + 60 * n];  // 30 contiguous pairs
#pragma unroll
        for (int m = 0; m < 30; ++m) {
            float rev = fmaf(p[2 * m], tv, p[2 * m + 1]);
            acc2[m] = fmaf(sin_rev(rev), s1n, acc2[m]);
        }
    }
    float sum2 = 0.0f;
    float s2v[30];
#pragma unroll
    for (int m = 0; m < 30; ++m) {
        s2v[m] = fmaf(0.5f, acc2[m], 0.5f * sum1);
        sum2 += s2v[m];
    }

    // ---- layer 3: fully unrolled, s2 stays in registers ----
    float acc3 = 0.0f;
#pragma unroll
    for (int n = 0; n < 30; ++n) {
        float rev = fmaf(g_P[2560 + 2 * n], tv, g_P[2560 + 2 * n + 1]);
        acc3 = fmaf(sin_rev(rev), s2v[n], acc3);
    }
    out[t] = fmaf(0.5f, acc3, 0.5f * sum2);
}

extern "C" void kernel_launch(void* const* d_in, const int* in_sizes, int n_in,
                              void* d_out, int out_size, void* d_ws, size_t ws_size,
                              hipStream_t stream) {
    (void)in_sizes; (void)n_in; (void)d_ws; (void)ws_size;
    const float* A0    = (const float*)d_in[1];
    const float* w0    = (const float*)d_in[2];
    const float* phi0  = (const float*)d_in[3];
    const float* wc0   = (const float*)d_in[4];
    const float* phic0 = (const float*)d_in[5];
    const float* w1    = (const float*)d_in[6];
    const float* phi1  = (const float*)d_in[7];
    const float* wc1   = (const float*)d_in[8];
    const float* phic1 = (const float*)d_in[9];
    const float* w2    = (const float*)d_in[10];
    const float* phi2  = (const float*)d_in[11];
    const float* wc2   = (const float*)d_in[12];
    const float* phic2 = (const float*)d_in[13];
    const float* w3    = (const float*)d_in[14];
    const float* phi3  = (const float*)d_in[15];
    const float* wc3   = (const float*)d_in[16];
    const float* phic3 = (const float*)d_in[17];

    float* out = (float*)d_out;

    hipLaunchKernelGGL(prep_kernel, dim3(11), dim3(256), 0, stream,
                       A0, w0, phi0, wc0, phic0,
                       w1, phi1, wc1, phic1,
                       w2, phi2, wc2, phic2,
                       w3, phi3, wc3, phic3);

    const int grid = (out_size + 63) / 64;   // 3125, exact
    hipLaunchKernelGGL(wave_main, dim3(grid), dim3(64), 0, stream, out);
}